// Round 1
// baseline (186.198 us; speedup 1.0000x reference)
//
#include <hip/hip_runtime.h>
#include <hip/hip_bf16.h>

// Problem constants (T,S,W,D,C,K) = (16,16,10,512,64,512)
#define T_  16
#define W_  10
#define D_  512
#define SW_ 160      // S*W
#define N1_ 1024     // 2*D
#define KT_ 512      // triplets per (t,w)

typedef __bf16 bf16x8 __attribute__((ext_vector_type(8)));
typedef float  f32x4  __attribute__((ext_vector_type(4)));

// async global->LDS, 16B per lane (global addr per-lane; LDS dest = wave base + lane*16)
__device__ __forceinline__ void async16(const void* g, void* l) {
  __builtin_amdgcn_global_load_lds(
      (__attribute__((address_space(1))) void*)(g),
      (__attribute__((address_space(3))) void*)(l), 16, 0, 0);
}

__device__ __forceinline__ float lo16(unsigned v) { return __uint_as_float(v << 16); }
__device__ __forceinline__ float hi16(unsigned v) { return __uint_as_float(v & 0xffff0000u); }

// ================= K0: prep_all — every cast/transpose/bias-fold in ONE launch
// blocks: [0,1280) cast x | [1280,2816) W1^T | [2816,3328) W2 cast
//         [3328,3840) W3^T | [3840,4352) W4 cast | [4352,4384) Wc^T
//         [4384,4388) b23 = 512*b2@W3 + b3 | [4388] bc4 = b4@Wc + bc
__global__ __launch_bounds__(256) void prep_all(
    const float* __restrict__ x_in, const float* __restrict__ W1,
    const float* __restrict__ W2, const float* __restrict__ W3,
    const float* __restrict__ W4, const float* __restrict__ Wc,
    const float* __restrict__ b2, const float* __restrict__ b3,
    const float* __restrict__ b4, const float* __restrict__ bc,
    __hip_bfloat16* __restrict__ xbf, __hip_bfloat16* __restrict__ w1t,
    __hip_bfloat16* __restrict__ w2b, __hip_bfloat16* __restrict__ w3t,
    __hip_bfloat16* __restrict__ w4b, __hip_bfloat16* __restrict__ wct,
    float* __restrict__ b23, float* __restrict__ bc4)
{
  __shared__ float tile[32 * 33];
  const int b = blockIdx.x, tid = threadIdx.x;

  auto cast4 = [&](const float* src, __hip_bfloat16* dst, int base) {
    int i = (base + tid) << 2;
    float4 v = *(const float4*)(src + i);
    __align__(8) __hip_bfloat16 o4[4];
    o4[0] = __float2bfloat16(v.x); o4[1] = __float2bfloat16(v.y);
    o4[2] = __float2bfloat16(v.z); o4[3] = __float2bfloat16(v.w);
    *(uint2*)(dst + i) = *(const uint2*)o4;
  };
  auto tr32 = [&](const float* src, __hip_bfloat16* dst, int R, int C, int rt, int ct) {
    int r0 = rt << 5, c0 = ct << 5;
    int c = tid & 31, rr = tid >> 5;
#pragma unroll
    for (int i = 0; i < 4; ++i) {
      int r = rr + i * 8;
      tile[r * 33 + c] = src[(size_t)(r0 + r) * C + c0 + c];
    }
    __syncthreads();
#pragma unroll
    for (int i = 0; i < 4; ++i) {
      int r = rr + i * 8;
      dst[(size_t)(c0 + r) * R + r0 + c] = __float2bfloat16(tile[c * 33 + r]);
    }
  };

  if (b < 1280) {
    cast4(x_in, xbf, b * 256);
  } else if (b < 2816) {
    int q = b - 1280; tr32(W1, w1t, 1536, 1024, q >> 5, q & 31);
  } else if (b < 3328) {
    cast4(W2, w2b, (b - 2816) * 256);
  } else if (b < 3840) {
    int q = b - 3328; tr32(W3, w3t, 512, 1024, q >> 5, q & 31);
  } else if (b < 4352) {
    cast4(W4, w4b, (b - 3840) * 256);
  } else if (b < 4384) {
    int q = b - 4352; tr32(Wc, wct, 512, 64, q >> 1, q & 1);
  } else if (b < 4388) {
    int c = (b - 4384) * 256 + tid;
    float s = 0.f;
#pragma unroll 8
    for (int j = 0; j < 512; ++j) s += b2[j] * W3[(size_t)j * 1024 + c];
    b23[c] = 512.f * s + b3[c];
  } else {
    if (tid < 64) {
      float s = 0.f;
#pragma unroll 8
      for (int j = 0; j < 512; ++j) s += b4[j] * Wc[(size_t)j * 64 + tid];
      bc4[tid] = s + bc[tid];
    }
  }
}

// ================= K1: group_kernel (blocks 0..511, unchanged logic)
//               + fused weight-product GEMMs (blocks 512..783):
//   w23t_cat[c][i]      = bf16_hi( sum_j W3t[c][j]*W2[i][j] ),  [c][1024+i] = lo residual
//   w4ct_cat[e][c]      = bf16_hi( sum_j Wct[e][j]*W4[c][j] ),  [e][1024+c] = lo residual
__global__ __launch_bounds__(256) void group_wgemm(
    const __hip_bfloat16* __restrict__ xbf,   // [16][160][512]
    const __hip_bfloat16* __restrict__ w1t,   // [1024][1536]
    const int* __restrict__ tidx,             // [16][10][3][512]
    const float* __restrict__ b1,             // [1024]
    __hip_bfloat16* __restrict__ Hsb,         // [160][1024] bf16
    const __hip_bfloat16* __restrict__ w3t,   // [1024][512]
    const __hip_bfloat16* __restrict__ w2b,   // [1024][512]
    const __hip_bfloat16* __restrict__ wct,   // [64][512]
    const __hip_bfloat16* __restrict__ w4b,   // [1024][512]
    __hip_bfloat16* __restrict__ w23t,        // [1024][2048] hi|lo
    __hip_bfloat16* __restrict__ w4ct)        // [64][2048]  hi|lo
{
  __shared__ __align__(16) char smem[43008];
  const int bx = blockIdx.x;
  const int tid = threadIdx.x;
  const int ln = tid & 63, wv = tid >> 6;
  const int col16 = ln & 15, quad = ln >> 4;

  if (bx >= 512) {
    // ---- fused weight GEMM: out[m][n] = sum_k A[m][k]*Bt[n][k], K=512, 64x64 tile
    const int b = bx - 512;
    const __hip_bfloat16 *A, *Bt;
    __hip_bfloat16* out;
    int m0, n0;
    if (b < 256) { A = w3t; Bt = w2b; out = w23t; m0 = (b >> 4) << 6; n0 = (b & 15) << 6; }
    else         { A = wct; Bt = w4b; out = w4ct; m0 = 0;             n0 = (b - 256) << 6; }
    char* Abuf = smem;              // 64 x 256B = 16384
    char* Bbuf = smem + 16384;      // 16384

    f32x4 acc[4];
#pragma unroll
    for (int a = 0; a < 4; ++a) acc[a] = (f32x4){0.f, 0.f, 0.f, 0.f};

#pragma unroll 1
    for (int kk = 0; kk < 512; kk += 128) {
      __syncthreads();
#pragma unroll
      for (int p = 0; p < 4; ++p) {           // A: 64 rows x 16 chunks
        int i = p * 256 + tid, r = i >> 4, q = i & 15;
        async16(A + (size_t)(m0 + r) * 512 + kk + ((q ^ (r & 7)) << 3), Abuf + (i << 4));
      }
#pragma unroll
      for (int p = 0; p < 4; ++p) {           // B: 64 rows x 16 chunks
        int i = p * 256 + tid, r = i >> 4, q = i & 15;
        async16(Bt + (size_t)(n0 + r) * 512 + kk + ((q ^ (r & 7)) << 3), Bbuf + (i << 4));
      }
      __syncthreads();

#pragma unroll
      for (int ks = 0; ks < 4; ++ks) {
        const int qq = (ks << 2) + quad;
        const int rn = (wv << 4) + col16;
        bf16x8 bfm = *(const bf16x8*)(Bbuf + rn * 256 + ((qq ^ (rn & 7)) << 4));
#pragma unroll
        for (int a = 0; a < 4; ++a) {
          int rm = (a << 4) + col16;
          bf16x8 af = *(const bf16x8*)(Abuf + rm * 256 + ((qq ^ (rm & 7)) << 4));
          acc[a] = __builtin_amdgcn_mfma_f32_16x16x32_bf16(af, bfm, acc[a], 0, 0, 0);
        }
      }
    }

    const int n = n0 + (wv << 4) + col16;
#pragma unroll
    for (int a = 0; a < 4; ++a)
#pragma unroll
      for (int r = 0; r < 4; ++r) {
        float v = acc[a][r];
        __hip_bfloat16 h = __float2bfloat16(v);
        float lres = v - __bfloat162float(h);
        size_t row = m0 + (a << 4) + (quad << 2) + r;
        out[row * 2048 + n] = h;
        out[row * 2048 + 1024 + n] = __float2bfloat16(lres);
      }
    return;
  }

  // ---------------- group part (proven; unchanged) ----------------
  char* Abuf  = smem;                      // [0, 20480)   phase 1
  char* Bbuf  = smem + 20480;              // [20480, 32768) phase 1
  char* Ptile = smem;                      // [0, 34560)   phase 2 (overlaps staging)
  int*  idx_s = (int*)(smem + 34560);      // 1536 ints = 6144 B
  float* red  = (float*)(smem + 40704);    // 4 waves x 32 cols = 512 B

  const int t   = bx >> 5;
  const int nt  = bx & 31;
  const int n0  = nt << 5;                 // 32-col output window

  const int wr = wv >> 1, wc = wv & 1;     // 2x2 wave grid: 80 rows x 48 cols each

  const __hip_bfloat16* xt = xbf + (size_t)t * (SW_ * D_);

  int aoff[5], lofA[5];
#pragma unroll
  for (int s = 0; s < 5; ++s) {            // A: 160 rows x 8 chunks = 1280
    int i = s * 256 + tid, r = i >> 3, q = i & 7;
    aoff[s] = r * 512 + ((q ^ (r & 7)) << 3);
    lofA[s] = i << 4;
  }
  int boff[3], lofB[3];
#pragma unroll
  for (int s = 0; s < 3; ++s) {            // B: 96 rows (j*32+nc) x 8 chunks = 768
    int i = s * 256 + tid, r = i >> 3, q = i & 7;
    int nc = r & 31, j = r >> 5;
    boff[s] = (n0 + nc) * 1536 + j * 512 + ((q ^ (r & 7)) << 3);
    lofB[s] = i << 4;
  }

  f32x4 acc[5][3];
#pragma unroll
  for (int a = 0; a < 5; ++a)
#pragma unroll
    for (int b = 0; b < 3; ++b)
      acc[a][b] = (f32x4){0.f, 0.f, 0.f, 0.f};

  // ---- phase 1: K-loop
#pragma unroll 1
  for (int kk = 0; kk < 512; kk += 64) {
    __syncthreads();
#pragma unroll
    for (int s = 0; s < 5; ++s) async16(xt + aoff[s] + kk, Abuf + lofA[s]);
#pragma unroll
    for (int s = 0; s < 3; ++s) async16(w1t + boff[s] + kk, Bbuf + lofB[s]);
    __syncthreads();

#pragma unroll
    for (int ks = 0; ks < 2; ++ks) {
      const int qq = (ks << 2) + quad;
      bf16x8 af[5], bfr[3];
#pragma unroll
      for (int a = 0; a < 5; ++a) {
        int rm = wr * 80 + a * 16 + col16;
        af[a] = *(const bf16x8*)(Abuf + rm * 128 + ((qq ^ (rm & 7)) << 4));
      }
#pragma unroll
      for (int b = 0; b < 3; ++b) {
        int rn = wc * 48 + b * 16 + col16;
        bfr[b] = *(const bf16x8*)(Bbuf + rn * 128 + ((qq ^ (rn & 7)) << 4));
      }
#pragma unroll
      for (int a = 0; a < 5; ++a)
#pragma unroll
        for (int b = 0; b < 3; ++b)
          acc[a][b] = __builtin_amdgcn_mfma_f32_16x16x32_bf16(af[a], bfr[b], acc[a][b], 0, 0, 0);
    }
  }

  __syncthreads();   // all staging reads done; smem now becomes Ptile

  // ---- write P to LDS as bf16, layout [j][sw][nc], row stride 72 B
#pragma unroll
  for (int a = 0; a < 5; ++a)
#pragma unroll
    for (int b = 0; b < 3; ++b) {
      int c = wc * 48 + b * 16 + col16;     // 0..95
      int j = c >> 5, nc = c & 31;
      int mb = wr * 80 + a * 16 + quad * 4;
#pragma unroll
      for (int r = 0; r < 4; ++r)
        *(__hip_bfloat16*)(Ptile + (j * 160 + mb + r) * 72 + nc * 2) =
            __float2bfloat16(acc[a][b][r]);
    }

  // ---- phase 2: gather + relu + reduce over k, per w
  const int nq = tid & 7;                   // 4 cols: nc = nq*4..+3
  const int kq = tid >> 3;                  // 0..31, k in [kq*16, kq*16+16)
  const float4 bias4 = *(const float4*)(b1 + n0 + (nq << 2));

#pragma unroll 1
  for (int w = 0; w < 10; ++w) {
    __syncthreads();                        // Ptile writes done / prev-w idx reads done
    {
      const int* src = tidx + (size_t)(t * 10 + w) * 1536;
      async16(src + (tid << 2), (char*)idx_s + (tid << 4));
      if (tid < 128) async16(src + 1024 + (tid << 2), (char*)idx_s + 4096 + (tid << 4));
    }
    __syncthreads();                        // idx ready (barrier drains vmcnt)

    f32x4 a4 = (f32x4){0.f, 0.f, 0.f, 0.f};
#pragma unroll
    for (int u = 0; u < 4; ++u) {
      const int kb = (kq << 4) + (u << 2);
      int4 i0 = *(const int4*)(idx_s + kb);
      int4 i1 = *(const int4*)(idx_s + 512 + kb);
      int4 i2 = *(const int4*)(idx_s + 1024 + kb);
#define STEP(IA, IB, IC)                                                          \
      {                                                                           \
        uint2 p0 = *(const uint2*)(Ptile + (IA) * 72 + (nq << 3));                \
        uint2 p1 = *(const uint2*)(Ptile + 11520 + (IB) * 72 + (nq << 3));        \
        uint2 p2 = *(const uint2*)(Ptile + 23040 + (IC) * 72 + (nq << 3));        \
        a4.x += fmaxf(lo16(p0.x) + lo16(p1.x) + lo16(p2.x) + bias4.x, 0.f);       \
        a4.y += fmaxf(hi16(p0.x) + hi16(p1.x) + hi16(p2.x) + bias4.y, 0.f);       \
        a4.z += fmaxf(lo16(p0.y) + lo16(p1.y) + lo16(p2.y) + bias4.z, 0.f);       \
        a4.w += fmaxf(hi16(p0.y) + hi16(p1.y) + hi16(p2.y) + bias4.w, 0.f);       \
      }
      STEP(i0.x, i1.x, i2.x)
      STEP(i0.y, i1.y, i2.y)
      STEP(i0.z, i1.z, i2.z)
      STEP(i0.w, i1.w, i2.w)
#undef STEP
    }

    // reduce over kq (lane bits 3..5), then across waves via LDS
#pragma unroll
    for (int off = 8; off <= 32; off <<= 1) {
      a4.x += __shfl_xor(a4.x, off);
      a4.y += __shfl_xor(a4.y, off);
      a4.z += __shfl_xor(a4.z, off);
      a4.w += __shfl_xor(a4.w, off);
    }
    if ((ln >> 3) == 0)
      *(f32x4*)(red + wv * 32 + (nq << 2)) = a4;
    __syncthreads();
    if (tid < 32) {
      float s = red[tid] + red[32 + tid] + red[64 + tid] + red[96 + tid];
      Hsb[(size_t)(t * 10 + w) * N1_ + n0 + tid] = __float2bfloat16(s);
    }
  }
}

// ================= K2: mid_gemm — u = relu(Hs @ W23(hi+lo) + b23), bf16 out.
// A=[160][1024], Bt=[1024][2048] (hi|lo), virtual K=2048 (A col = kk&1023), BK=256.
// Grid (16,2): block = 80 rows x 64 cols.
__global__ __launch_bounds__(256) void mid_gemm(
    const __hip_bfloat16* __restrict__ A,
    const __hip_bfloat16* __restrict__ Bt,
    const float* __restrict__ bias,
    __hip_bfloat16* __restrict__ out)
{
  __shared__ __align__(16) char Abuf[40960];  // 80 rows x 512 B
  __shared__ __align__(16) char Bbuf[32768];  // 64 rows x 512 B
  const int tid = threadIdx.x;
  const int n0 = blockIdx.x << 6;
  const int m0 = blockIdx.y * 80;
  const int ln = tid & 63, wv = tid >> 6;
  const int col16 = ln & 15, quad = ln >> 4;

  f32x4 acc[5];
#pragma unroll
  for (int a = 0; a < 5; ++a) acc[a] = (f32x4){0.f, 0.f, 0.f, 0.f};

#pragma unroll 1
  for (int kk = 0; kk < 2048; kk += 256) {
    const int ka = kk & 1023;
    __syncthreads();
#pragma unroll
    for (int p = 0; p < 10; ++p) {          // A: 80 rows x 32 chunks
      int i = p * 256 + tid, r = i >> 5, q = i & 31;
      async16(A + (size_t)(m0 + r) * 1024 + ka + ((q ^ (r & 7)) << 3), Abuf + (i << 4));
    }
#pragma unroll
    for (int p = 0; p < 8; ++p) {           // B: 64 rows x 32 chunks
      int i = p * 256 + tid, r = i >> 5, q = i & 31;
      async16(Bt + (size_t)(n0 + r) * 2048 + kk + ((q ^ (r & 7)) << 3), Bbuf + (i << 4));
    }
    __syncthreads();

#pragma unroll
    for (int ks = 0; ks < 8; ++ks) {
      const int qq = (ks << 2) + quad;
      const int rn = (wv << 4) + col16;
      bf16x8 bfm = *(const bf16x8*)(Bbuf + rn * 512 + ((qq ^ (rn & 7)) << 4));
#pragma unroll
      for (int a = 0; a < 5; ++a) {
        int rm = (a << 4) + col16;
        bf16x8 af = *(const bf16x8*)(Abuf + rm * 512 + ((qq ^ (rm & 7)) << 4));
        acc[a] = __builtin_amdgcn_mfma_f32_16x16x32_bf16(af, bfm, acc[a], 0, 0, 0);
      }
    }
  }

  const int n = n0 + (wv << 4) + col16;
  const float bb = bias[n];
#pragma unroll
  for (int a = 0; a < 5; ++a)
#pragma unroll
    for (int r = 0; r < 4; ++r) {
      float v = fmaxf(acc[a][r] + bb, 0.f);
      out[(size_t)(m0 + (a << 4) + (quad << 2) + r) * 1024 + n] = __float2bfloat16(v);
    }
}

// ================= K3: head — score = u @ W4c(hi+lo) + bc4, softmax over 64.
// A=[160][1024], Bt=[64][2048] (hi|lo), virtual K=2048, BK=256. Grid 2: 80 rows/block.
__global__ __launch_bounds__(256) void head_gemm2(
    const __hip_bfloat16* __restrict__ A,
    const __hip_bfloat16* __restrict__ Bt,
    const float* __restrict__ bc4,
    float* __restrict__ out)                 // [160][64]
{
  __shared__ __align__(16) char Abuf[40960];
  __shared__ __align__(16) char Bbuf[32768];
  __shared__ float sc[80 * 64];
  __shared__ float rs[80];
  const int tid = threadIdx.x;
  const int m0 = blockIdx.x * 80;
  const int ln = tid & 63, wv = tid >> 6;
  const int col16 = ln & 15, quad = ln >> 4;

  f32x4 acc[5];
#pragma unroll
  for (int a = 0; a < 5; ++a) acc[a] = (f32x4){0.f, 0.f, 0.f, 0.f};

#pragma unroll 1
  for (int kk = 0; kk < 2048; kk += 256) {
    const int ka = kk & 1023;
    __syncthreads();
#pragma unroll
    for (int p = 0; p < 10; ++p) {
      int i = p * 256 + tid, r = i >> 5, q = i & 31;
      async16(A + (size_t)(m0 + r) * 1024 + ka + ((q ^ (r & 7)) << 3), Abuf + (i << 4));
    }
#pragma unroll
    for (int p = 0; p < 8; ++p) {
      int i = p * 256 + tid, r = i >> 5, q = i & 31;
      async16(Bt + (size_t)r * 2048 + kk + ((q ^ (r & 7)) << 3), Bbuf + (i << 4));
    }
    __syncthreads();

#pragma unroll
    for (int ks = 0; ks < 8; ++ks) {
      const int qq = (ks << 2) + quad;
      const int rn = (wv << 4) + col16;
      bf16x8 bfm = *(const bf16x8*)(Bbuf + rn * 512 + ((qq ^ (rn & 7)) << 4));
#pragma unroll
      for (int a = 0; a < 5; ++a) {
        int rm = (a << 4) + col16;
        bf16x8 af = *(const bf16x8*)(Abuf + rm * 512 + ((qq ^ (rm & 7)) << 4));
        acc[a] = __builtin_amdgcn_mfma_f32_16x16x32_bf16(af, bfm, acc[a], 0, 0, 0);
      }
    }
  }

  const int n = (wv << 4) + col16;
  const float bb = bc4[n];
#pragma unroll
  for (int a = 0; a < 5; ++a)
#pragma unroll
    for (int r = 0; r < 4; ++r)
      sc[((a << 4) + (quad << 2) + r) * 64 + n] = acc[a][r] + bb;
  __syncthreads();

  if (tid < 80) {
    float m = -1e30f;
    for (int c = 0; c < 64; ++c) m = fmaxf(m, sc[tid * 64 + c]);
    float s = 0.f;
    for (int c = 0; c < 64; ++c) {
      float e = expf(sc[tid * 64 + c] - m);
      sc[tid * 64 + c] = e;
      s += e;
    }
    rs[tid] = 1.f / s;
  }
  __syncthreads();
#pragma unroll
  for (int p = 0; p < 20; ++p) {
    int f = p * 256 + tid, r = f >> 6, c = f & 63;
    out[(size_t)(m0 + r) * 64 + c] = sc[f] * rs[r];
  }
}

extern "C" void kernel_launch(void* const* d_in, const int* in_sizes, int n_in,
                              void* d_out, int out_size, void* d_ws, size_t ws_size,
                              hipStream_t stream) {
  const float* x_in = (const float*)d_in[0];
  const int*   tidx = (const int*)d_in[1];
  const float* W1 = (const float*)d_in[2];
  const float* b1 = (const float*)d_in[3];
  const float* W2 = (const float*)d_in[4];
  const float* b2 = (const float*)d_in[5];
  const float* W3 = (const float*)d_in[6];
  const float* b3 = (const float*)d_in[7];
  const float* W4 = (const float*)d_in[8];
  const float* b4 = (const float*)d_in[9];
  const float* Wc = (const float*)d_in[10];
  const float* bc = (const float*)d_in[11];
  float* out = (float*)d_out;
  (void)in_sizes; (void)n_in; (void)out_size; (void)ws_size;

  char* ws = (char*)d_ws;
  __hip_bfloat16* xbf  = (__hip_bfloat16*)(ws + 0);         // [16][160][512]   2,621,440
  __hip_bfloat16* w1t  = (__hip_bfloat16*)(ws + 2621440);   // [1024][1536]     3,145,728
  __hip_bfloat16* w2b  = (__hip_bfloat16*)(ws + 5767168);   // [1024][512]      1,048,576
  __hip_bfloat16* w3t  = (__hip_bfloat16*)(ws + 6815744);   // [1024][512]      1,048,576
  __hip_bfloat16* w4b  = (__hip_bfloat16*)(ws + 7864320);   // [1024][512]      1,048,576
  __hip_bfloat16* wct  = (__hip_bfloat16*)(ws + 8912896);   // [64][512]           65,536
  float*          b23  = (float*)         (ws + 8978432);   // [1024]               4,096
  float*          bc4  = (float*)         (ws + 8982528);   // [64]                   256
  __hip_bfloat16* Hsb  = (__hip_bfloat16*)(ws + 8982784);   // [160][1024]        327,680
  __hip_bfloat16* w23t = (__hip_bfloat16*)(ws + 9310464);   // [1024][2048]     4,194,304
  __hip_bfloat16* w4ct = (__hip_bfloat16*)(ws + 13504768);  // [64][2048]         262,144
  __hip_bfloat16* ub   = (__hip_bfloat16*)(ws + 13766912);  // [160][1024]        327,680

  // K0: all casts/transposes + bias folds (one launch)
  prep_all<<<4389, 256, 0, stream>>>(x_in, W1, W2, W3, W4, Wc, b2, b3, b4, bc,
                                     xbf, w1t, w2b, w3t, w4b, wct, b23, bc4);

  // K1: group compute (512 blocks) + overlapped weight-product GEMMs (272 blocks)
  group_wgemm<<<784, 256, 0, stream>>>(xbf, w1t, tidx, b1, Hsb,
                                       w3t, w2b, wct, w4b, w23t, w4ct);

  // K2: u = relu(Hs @ W23 + b23)
  mid_gemm<<<dim3(16, 2), 256, 0, stream>>>(Hsb, w23t, b23, ub);

  // K3: softmax(u @ W4c + bc4)
  head_gemm2<<<2, 256, 0, stream>>>(ub, w4ct, bc4, out);
}

// Round 2
// 156.264 us; speedup vs baseline: 1.1916x; 1.1916x over previous
//
#include <hip/hip_runtime.h>
#include <hip/hip_bf16.h>

// Problem constants (T,S,W,D,C,K) = (16,16,10,512,64,512)
#define T_  16
#define W_  10
#define D_  512
#define SW_ 160      // S*W
#define N1_ 1024     // 2*D
#define KT_ 512      // triplets per (t,w)

typedef __bf16 bf16x8 __attribute__((ext_vector_type(8)));
typedef _Float16 f16x8 __attribute__((ext_vector_type(8)));
typedef float  f32x4  __attribute__((ext_vector_type(4)));
typedef float  f32x2  __attribute__((ext_vector_type(2)));

// async global->LDS, 16B per lane (global addr per-lane; LDS dest = wave base + lane*16)
__device__ __forceinline__ void async16(const void* g, void* l) {
  __builtin_amdgcn_global_load_lds(
      (__attribute__((address_space(1))) void*)(g),
      (__attribute__((address_space(3))) void*)(l), 16, 0, 0);
}

// unpack a bf16 pair word into f32x2 {lo, hi} (bit-shift trick, 2 VALU)
__device__ __forceinline__ f32x2 unpk(unsigned v) {
  return (f32x2){__uint_as_float(v << 16), __uint_as_float(v & 0xffff0000u)};
}
__device__ __forceinline__ f32x2 max0(f32x2 v) {
  return (f32x2){fmaxf(v.x, 0.f), fmaxf(v.y, 0.f)};
}

// ================= K0: prep_all — every cast/transpose/bias-fold in ONE launch
// blocks: [0,1280) cast x(bf16) | [1280,2816) W1^T(bf16) | [2816,3328) W2 cast(fp16)
//         [3328,3840) W3^T(fp16) | [3840,4352) W4 cast(fp16) | [4352,4384) Wc^T(fp16)
//         [4384,4388) b23 = 512*b2@W3 + b3 | [4388] bc4 = b4@Wc + bc
__global__ __launch_bounds__(256) void prep_all(
    const float* __restrict__ x_in, const float* __restrict__ W1,
    const float* __restrict__ W2, const float* __restrict__ W3,
    const float* __restrict__ W4, const float* __restrict__ Wc,
    const float* __restrict__ b2, const float* __restrict__ b3,
    const float* __restrict__ b4, const float* __restrict__ bc,
    __hip_bfloat16* __restrict__ xbf, __hip_bfloat16* __restrict__ w1t,
    _Float16* __restrict__ w2b, _Float16* __restrict__ w3t,
    _Float16* __restrict__ w4b, _Float16* __restrict__ wct,
    float* __restrict__ b23, float* __restrict__ bc4)
{
  __shared__ float tile[32 * 33];
  const int b = blockIdx.x, tid = threadIdx.x;

  auto cast4h = [&](const float* src, _Float16* dst, int base) {
    int i = (base + tid) << 2;
    float4 v = *(const float4*)(src + i);
    __align__(8) _Float16 o4[4] = {(_Float16)v.x, (_Float16)v.y,
                                   (_Float16)v.z, (_Float16)v.w};
    *(uint2*)(dst + i) = *(const uint2*)o4;
  };
  auto tr32h = [&](const float* src, _Float16* dst, int R, int C, int rt, int ct) {
    int r0 = rt << 5, c0 = ct << 5;
    int c = tid & 31, rr = tid >> 5;
#pragma unroll
    for (int i = 0; i < 4; ++i) {
      int r = rr + i * 8;
      tile[r * 33 + c] = src[(size_t)(r0 + r) * C + c0 + c];
    }
    __syncthreads();
#pragma unroll
    for (int i = 0; i < 4; ++i) {
      int r = rr + i * 8;
      dst[(size_t)(c0 + r) * R + r0 + c] = (_Float16)tile[c * 33 + r];
    }
  };

  if (b < 1280) {
    int i = (b * 256 + tid) << 2;
    float4 v = *(const float4*)(x_in + i);
    __align__(8) __hip_bfloat16 o4[4];
    o4[0] = __float2bfloat16(v.x); o4[1] = __float2bfloat16(v.y);
    o4[2] = __float2bfloat16(v.z); o4[3] = __float2bfloat16(v.w);
    *(uint2*)(xbf + i) = *(const uint2*)o4;
  } else if (b < 2816) {
    int q = b - 1280;
    int r0 = (q >> 5) << 5, c0 = (q & 31) << 5;
    int c = tid & 31, rr = tid >> 5;
#pragma unroll
    for (int i = 0; i < 4; ++i) {
      int r = rr + i * 8;
      tile[r * 33 + c] = W1[(size_t)(r0 + r) * 1024 + c0 + c];
    }
    __syncthreads();
#pragma unroll
    for (int i = 0; i < 4; ++i) {
      int r = rr + i * 8;
      w1t[(size_t)(c0 + r) * 1536 + r0 + c] = __float2bfloat16(tile[c * 33 + r]);
    }
  } else if (b < 3328) {
    cast4h(W2, w2b, (b - 2816) * 256);
  } else if (b < 3840) {
    int q = b - 3328; tr32h(W3, w3t, 512, 1024, q >> 5, q & 31);
  } else if (b < 4352) {
    cast4h(W4, w4b, (b - 3840) * 256);
  } else if (b < 4384) {
    int q = b - 4352; tr32h(Wc, wct, 512, 64, q >> 1, q & 1);
  } else if (b < 4388) {
    int c = (b - 4384) * 256 + tid;
    float s = 0.f;
#pragma unroll 32
    for (int j = 0; j < 512; ++j) s += b2[j] * W3[(size_t)j * 1024 + c];
    b23[c] = 512.f * s + b3[c];
  } else {
    if (tid < 64) {
      float s = 0.f;
#pragma unroll 32
      for (int j = 0; j < 512; ++j) s += b4[j] * Wc[(size_t)j * 64 + tid];
      bc4[tid] = s + bc[tid];
    }
  }
}

// ================= K1: group blocks 0..511 + fused weight-product GEMM blocks 512..783
//   w23t[c][i] = fp16( sum_j W3t[c][j]*W2[i][j] )   -> Bt layout [1024][1024] for mid
//   w4ct[e][c] = fp16( sum_j Wct[e][j]*W4[c][j] )   -> Bt layout [64][1024]  for head
__global__ __launch_bounds__(256) void group_wgemm(
    const __hip_bfloat16* __restrict__ xbf,   // [16][160][512]
    const __hip_bfloat16* __restrict__ w1t,   // [1024][1536]
    const int* __restrict__ tidx,             // [16][10][3][512]
    const float* __restrict__ b1,             // [1024]
    _Float16* __restrict__ Hsb,               // [160][1024] fp16
    const _Float16* __restrict__ w3t,         // [1024][512]
    const _Float16* __restrict__ w2b,         // [1024][512]
    const _Float16* __restrict__ wct,         // [64][512]
    const _Float16* __restrict__ w4b,         // [1024][512]
    _Float16* __restrict__ w23t,              // [1024][1024]
    _Float16* __restrict__ w4ct)              // [64][1024]
{
  __shared__ __align__(16) char smem[47360];
  const int bx = blockIdx.x;
  const int tid = threadIdx.x;
  const int ln = tid & 63, wv = tid >> 6;
  const int col16 = ln & 15, quad = ln >> 4;

  if (bx >= 512) {
    // ---- weight GEMM: out[m][n] = sum_k A[m][k]*Bt[n][k], K=512 fp16, 64x64 tile
    const int b = bx - 512;
    const _Float16 *A, *Bt;
    _Float16* out;
    int m0, n0;
    if (b < 256) { A = w3t; Bt = w2b; out = w23t; m0 = (b >> 4) << 6; n0 = (b & 15) << 6; }
    else         { A = wct; Bt = w4b; out = w4ct; m0 = 0;             n0 = (b - 256) << 6; }
    char* Abuf = smem;              // 64 x 256B = 16384
    char* Bbuf = smem + 16384;      // 16384

    f32x4 acc[4];
#pragma unroll
    for (int a = 0; a < 4; ++a) acc[a] = (f32x4){0.f, 0.f, 0.f, 0.f};

#pragma unroll 1
    for (int kk = 0; kk < 512; kk += 128) {
      __syncthreads();
#pragma unroll
      for (int p = 0; p < 4; ++p) {           // A: 64 rows x 16 chunks
        int i = p * 256 + tid, r = i >> 4, q = i & 15;
        async16(A + (size_t)(m0 + r) * 512 + kk + ((q ^ (r & 7)) << 3), Abuf + (i << 4));
      }
#pragma unroll
      for (int p = 0; p < 4; ++p) {           // B: 64 rows x 16 chunks
        int i = p * 256 + tid, r = i >> 4, q = i & 15;
        async16(Bt + (size_t)(n0 + r) * 512 + kk + ((q ^ (r & 7)) << 3), Bbuf + (i << 4));
      }
      __syncthreads();

#pragma unroll
      for (int ks = 0; ks < 4; ++ks) {
        const int qq = (ks << 2) + quad;
        const int rn = (wv << 4) + col16;
        f16x8 bfm = *(const f16x8*)(Bbuf + rn * 256 + ((qq ^ (rn & 7)) << 4));
#pragma unroll
        for (int a = 0; a < 4; ++a) {
          int rm = (a << 4) + col16;
          f16x8 af = *(const f16x8*)(Abuf + rm * 256 + ((qq ^ (rm & 7)) << 4));
          acc[a] = __builtin_amdgcn_mfma_f32_16x16x32_f16(af, bfm, acc[a], 0, 0, 0);
        }
      }
    }

    const int n = n0 + (wv << 4) + col16;
#pragma unroll
    for (int a = 0; a < 4; ++a)
#pragma unroll
      for (int r = 0; r < 4; ++r) {
        size_t row = m0 + (a << 4) + (quad << 2) + r;
        out[row * 1024 + n] = (_Float16)acc[a][r];
      }
    return;
  }

  // ---------------- group part ----------------
  char* Abuf  = smem;                      // [0, 20480)   phase 1
  char* Bbuf  = smem + 20480;              // [20480, 32768) phase 1
  char* Ptile = smem;                      // [0, 34560)   phase 2 (overlaps staging)
  int*  idxA  = (int*)(smem + 34560);      // 1536 ints = 6144 B
  int*  idxB  = (int*)(smem + 40704);      // second idx buffer
  float* red  = (float*)(smem + 46848);    // 4 waves x 32 cols = 512 B

  const int t   = bx >> 5;
  const int nt  = bx & 31;
  const int n0  = nt << 5;                 // 32-col output window

  const int wr = wv >> 1, wc = wv & 1;     // 2x2 wave grid: 80 rows x 48 cols each

  const __hip_bfloat16* xt = xbf + (size_t)t * (SW_ * D_);

  int aoff[5], lofA[5];
#pragma unroll
  for (int s = 0; s < 5; ++s) {            // A: 160 rows x 8 chunks = 1280
    int i = s * 256 + tid, r = i >> 3, q = i & 7;
    aoff[s] = r * 512 + ((q ^ (r & 7)) << 3);
    lofA[s] = i << 4;
  }
  int boff[3], lofB[3];
#pragma unroll
  for (int s = 0; s < 3; ++s) {            // B: 96 rows (j*32+nc) x 8 chunks = 768
    int i = s * 256 + tid, r = i >> 3, q = i & 7;
    int nc = r & 31, j = r >> 5;
    boff[s] = (n0 + nc) * 1536 + j * 512 + ((q ^ (r & 7)) << 3);
    lofB[s] = i << 4;
  }

  f32x4 acc[5][3];
#pragma unroll
  for (int a = 0; a < 5; ++a)
#pragma unroll
    for (int b = 0; b < 3; ++b)
      acc[a][b] = (f32x4){0.f, 0.f, 0.f, 0.f};

  // ---- phase 1: K-loop
#pragma unroll 1
  for (int kk = 0; kk < 512; kk += 64) {
    __syncthreads();
#pragma unroll
    for (int s = 0; s < 5; ++s) async16(xt + aoff[s] + kk, Abuf + lofA[s]);
#pragma unroll
    for (int s = 0; s < 3; ++s) async16(w1t + boff[s] + kk, Bbuf + lofB[s]);
    __syncthreads();

#pragma unroll
    for (int ks = 0; ks < 2; ++ks) {
      const int qq = (ks << 2) + quad;
      bf16x8 af[5], bfr[3];
#pragma unroll
      for (int a = 0; a < 5; ++a) {
        int rm = wr * 80 + a * 16 + col16;
        af[a] = *(const bf16x8*)(Abuf + rm * 128 + ((qq ^ (rm & 7)) << 4));
      }
#pragma unroll
      for (int b = 0; b < 3; ++b) {
        int rn = wc * 48 + b * 16 + col16;
        bfr[b] = *(const bf16x8*)(Bbuf + rn * 128 + ((qq ^ (rn & 7)) << 4));
      }
#pragma unroll
      for (int a = 0; a < 5; ++a)
#pragma unroll
        for (int b = 0; b < 3; ++b)
          acc[a][b] = __builtin_amdgcn_mfma_f32_16x16x32_bf16(af[a], bfr[b], acc[a][b], 0, 0, 0);
    }
  }

  __syncthreads();   // all staging reads done; smem now becomes Ptile

  // ---- write P to LDS as bf16, layout [j][sw][nc], row stride 72 B
#pragma unroll
  for (int a = 0; a < 5; ++a)
#pragma unroll
    for (int b = 0; b < 3; ++b) {
      int c = wc * 48 + b * 16 + col16;     // 0..95
      int j = c >> 5, nc = c & 31;
      int mb = wr * 80 + a * 16 + quad * 4;
#pragma unroll
      for (int r = 0; r < 4; ++r)
        *(__hip_bfloat16*)(Ptile + (j * 160 + mb + r) * 72 + nc * 2) =
            __float2bfloat16(acc[a][b][r]);
    }

  // ---- phase 2: gather + relu + reduce over k, per w (idx double-buffered,
  //      indices pre-scaled by 72-B row stride at staging time)
  const int nq = tid & 7;                   // 4 cols: nc = nq*4..+3
  const int kq = tid >> 3;                  // 0..31, k in [kq*16, kq*16+16)
  const float4 bias4 = *(const float4*)(b1 + n0 + (nq << 2));
  const f32x2 bl = (f32x2){bias4.x, bias4.y};
  const f32x2 bh = (f32x2){bias4.z, bias4.w};
  const char* Pt0 = Ptile + (nq << 3);
  const char* Pt1 = Pt0 + 11520;
  const char* Pt2 = Pt0 + 23040;

  const int* tsrc = tidx + (size_t)t * 10 * 1536;
  int4 ra = make_int4(0, 0, 0, 0), rb = make_int4(0, 0, 0, 0);
  auto sst = [&](int* dst, int4 a, int4 b) {   // scale by 72 and store to LDS
    *(int4*)(dst + (tid << 2)) = make_int4(a.x * 72, a.y * 72, a.z * 72, a.w * 72);
    if (tid < 128)
      *(int4*)(dst + 1024 + (tid << 2)) = make_int4(b.x * 72, b.y * 72, b.z * 72, b.w * 72);
  };

  // prologue: stage w=0 indices
  ra = *(const int4*)(tsrc + (tid << 2));
  if (tid < 128) rb = *(const int4*)(tsrc + 1024 + (tid << 2));
  sst(idxA, ra, rb);
  int* cur = idxA;
  int* nxt = idxB;

#pragma unroll 1
  for (int w = 0; w < 10; ++w) {
    __syncthreads();       // cur idx + Ptile visible; red(w-1) consumed
    if (w < 9) {           // issue next-w idx loads (latency hidden under gather)
      const int* s2 = tsrc + (w + 1) * 1536;
      ra = *(const int4*)(s2 + (tid << 2));
      if (tid < 128) rb = *(const int4*)(s2 + 1024 + (tid << 2));
    }

    f32x2 z2 = (f32x2){0.f, 0.f};
    f32x2 acc01 = z2, acc23 = z2;
#pragma unroll
    for (int u = 0; u < 4; ++u) {
      const int kb = (kq << 4) + (u << 2);
      int4 i0 = *(const int4*)(cur + kb);
      int4 i1 = *(const int4*)(cur + 512 + kb);
      int4 i2 = *(const int4*)(cur + 1024 + kb);
#define STEP(IA, IB, IC)                                                  \
      {                                                                   \
        uint2 p0 = *(const uint2*)(Pt0 + (IA));                           \
        uint2 p1 = *(const uint2*)(Pt1 + (IB));                           \
        uint2 p2 = *(const uint2*)(Pt2 + (IC));                           \
        f32x2 s0 = (unpk(p0.x) + unpk(p1.x)) + (unpk(p2.x) + bl);         \
        f32x2 s1 = (unpk(p0.y) + unpk(p1.y)) + (unpk(p2.y) + bh);         \
        acc01 += max0(s0);                                                \
        acc23 += max0(s1);                                                \
      }
      STEP(i0.x, i1.x, i2.x)
      STEP(i0.y, i1.y, i2.y)
      STEP(i0.z, i1.z, i2.z)
      STEP(i0.w, i1.w, i2.w)
#undef STEP
    }

    if (w < 9) sst(nxt, ra, rb);    // store next-w idx into other buffer

    // reduce over kq (lane bits 3..5), then across waves via LDS
    f32x4 a4 = (f32x4){acc01.x, acc01.y, acc23.x, acc23.y};
#pragma unroll
    for (int off = 8; off <= 32; off <<= 1) {
      a4.x += __shfl_xor(a4.x, off);
      a4.y += __shfl_xor(a4.y, off);
      a4.z += __shfl_xor(a4.z, off);
      a4.w += __shfl_xor(a4.w, off);
    }
    if ((ln >> 3) == 0)
      *(f32x4*)(red + wv * 32 + (nq << 2)) = a4;
    __syncthreads();
    if (tid < 32) {
      float s = red[tid] + red[32 + tid] + red[64 + tid] + red[96 + tid];
      Hsb[(size_t)(t * 10 + w) * N1_ + n0 + tid] = (_Float16)s;
    }
    int* tmp = cur; cur = nxt; nxt = tmp;
  }
}

// ================= K2: mid_gemm — u = relu(Hs @ W23 + b23), fp16 in/out, K=1024.
// Grid (16,2): block = 80 rows x 64 cols, BK=256 -> 4 iters.
__global__ __launch_bounds__(256) void mid_gemm(
    const _Float16* __restrict__ A,          // [160][1024]
    const _Float16* __restrict__ Bt,         // [1024][1024]
    const float* __restrict__ bias,
    _Float16* __restrict__ out)              // [160][1024]
{
  __shared__ __align__(16) char Abuf[40960];  // 80 rows x 512 B
  __shared__ __align__(16) char Bbuf[32768];  // 64 rows x 512 B
  const int tid = threadIdx.x;
  const int n0 = blockIdx.x << 6;
  const int m0 = blockIdx.y * 80;
  const int ln = tid & 63, wv = tid >> 6;
  const int col16 = ln & 15, quad = ln >> 4;

  f32x4 acc[5];
#pragma unroll
  for (int a = 0; a < 5; ++a) acc[a] = (f32x4){0.f, 0.f, 0.f, 0.f};

#pragma unroll 1
  for (int kk = 0; kk < 1024; kk += 256) {
    __syncthreads();
#pragma unroll
    for (int p = 0; p < 10; ++p) {          // A: 80 rows x 32 chunks
      int i = p * 256 + tid, r = i >> 5, q = i & 31;
      async16(A + (size_t)(m0 + r) * 1024 + kk + ((q ^ (r & 7)) << 3), Abuf + (i << 4));
    }
#pragma unroll
    for (int p = 0; p < 8; ++p) {           // B: 64 rows x 32 chunks
      int i = p * 256 + tid, r = i >> 5, q = i & 31;
      async16(Bt + (size_t)(n0 + r) * 1024 + kk + ((q ^ (r & 7)) << 3), Bbuf + (i << 4));
    }
    __syncthreads();

#pragma unroll
    for (int ks = 0; ks < 8; ++ks) {
      const int qq = (ks << 2) + quad;
      const int rn = (wv << 4) + col16;
      f16x8 bfm = *(const f16x8*)(Bbuf + rn * 512 + ((qq ^ (rn & 7)) << 4));
#pragma unroll
      for (int a = 0; a < 5; ++a) {
        int rm = (a << 4) + col16;
        f16x8 af = *(const f16x8*)(Abuf + rm * 512 + ((qq ^ (rm & 7)) << 4));
        acc[a] = __builtin_amdgcn_mfma_f32_16x16x32_f16(af, bfm, acc[a], 0, 0, 0);
      }
    }
  }

  const int n = n0 + (wv << 4) + col16;
  const float bb = bias[n];
#pragma unroll
  for (int a = 0; a < 5; ++a)
#pragma unroll
    for (int r = 0; r < 4; ++r) {
      float v = fmaxf(acc[a][r] + bb, 0.f);
      out[(size_t)(m0 + (a << 4) + (quad << 2) + r) * 1024 + n] = (_Float16)v;
    }
}

// ================= K3: head — score = u @ W4c + bc4, softmax over 64. fp16 in, K=1024.
__global__ __launch_bounds__(256) void head_gemm2(
    const _Float16* __restrict__ A,          // [160][1024]
    const _Float16* __restrict__ Bt,         // [64][1024]
    const float* __restrict__ bc4,
    float* __restrict__ out)                 // [160][64]
{
  __shared__ __align__(16) char Abuf[40960];
  __shared__ __align__(16) char Bbuf[32768];
  __shared__ float sc[80 * 64];
  __shared__ float rs[80];
  const int tid = threadIdx.x;
  const int m0 = blockIdx.x * 80;
  const int ln = tid & 63, wv = tid >> 6;
  const int col16 = ln & 15, quad = ln >> 4;

  f32x4 acc[5];
#pragma unroll
  for (int a = 0; a < 5; ++a) acc[a] = (f32x4){0.f, 0.f, 0.f, 0.f};

#pragma unroll 1
  for (int kk = 0; kk < 1024; kk += 256) {
    __syncthreads();
#pragma unroll
    for (int p = 0; p < 10; ++p) {
      int i = p * 256 + tid, r = i >> 5, q = i & 31;
      async16(A + (size_t)(m0 + r) * 1024 + kk + ((q ^ (r & 7)) << 3), Abuf + (i << 4));
    }
#pragma unroll
    for (int p = 0; p < 8; ++p) {
      int i = p * 256 + tid, r = i >> 5, q = i & 31;
      async16(Bt + (size_t)r * 1024 + kk + ((q ^ (r & 7)) << 3), Bbuf + (i << 4));
    }
    __syncthreads();

#pragma unroll
    for (int ks = 0; ks < 8; ++ks) {
      const int qq = (ks << 2) + quad;
      const int rn = (wv << 4) + col16;
      f16x8 bfm = *(const f16x8*)(Bbuf + rn * 512 + ((qq ^ (rn & 7)) << 4));
#pragma unroll
      for (int a = 0; a < 5; ++a) {
        int rm = (a << 4) + col16;
        f16x8 af = *(const f16x8*)(Abuf + rm * 512 + ((qq ^ (rm & 7)) << 4));
        acc[a] = __builtin_amdgcn_mfma_f32_16x16x32_f16(af, bfm, acc[a], 0, 0, 0);
      }
    }
  }

  const int n = (wv << 4) + col16;
  const float bb = bc4[n];
#pragma unroll
  for (int a = 0; a < 5; ++a)
#pragma unroll
    for (int r = 0; r < 4; ++r)
      sc[((a << 4) + (quad << 2) + r) * 64 + n] = acc[a][r] + bb;
  __syncthreads();

  if (tid < 80) {
    float m = -1e30f;
    for (int c = 0; c < 64; ++c) m = fmaxf(m, sc[tid * 64 + c]);
    float s = 0.f;
    for (int c = 0; c < 64; ++c) {
      float e = expf(sc[tid * 64 + c] - m);
      sc[tid * 64 + c] = e;
      s += e;
    }
    rs[tid] = 1.f / s;
  }
  __syncthreads();
#pragma unroll
  for (int p = 0; p < 20; ++p) {
    int f = p * 256 + tid, r = f >> 6, c = f & 63;
    out[(size_t)(m0 + r) * 64 + c] = sc[f] * rs[r];
  }
}

extern "C" void kernel_launch(void* const* d_in, const int* in_sizes, int n_in,
                              void* d_out, int out_size, void* d_ws, size_t ws_size,
                              hipStream_t stream) {
  const float* x_in = (const float*)d_in[0];
  const int*   tidx = (const int*)d_in[1];
  const float* W1 = (const float*)d_in[2];
  const float* b1 = (const float*)d_in[3];
  const float* W2 = (const float*)d_in[4];
  const float* b2 = (const float*)d_in[5];
  const float* W3 = (const float*)d_in[6];
  const float* b3 = (const float*)d_in[7];
  const float* W4 = (const float*)d_in[8];
  const float* b4 = (const float*)d_in[9];
  const float* Wc = (const float*)d_in[10];
  const float* bc = (const float*)d_in[11];
  float* out = (float*)d_out;
  (void)in_sizes; (void)n_in; (void)out_size; (void)ws_size;

  char* ws = (char*)d_ws;
  __hip_bfloat16* xbf  = (__hip_bfloat16*)(ws + 0);         // 2,621,440
  __hip_bfloat16* w1t  = (__hip_bfloat16*)(ws + 2621440);   // 3,145,728 -> 5,767,168
  _Float16*       w2b  = (_Float16*)      (ws + 5767168);   // [1024][512] 1,048,576
  _Float16*       w3t  = (_Float16*)      (ws + 6815744);   // [1024][512] 1,048,576
  _Float16*       w4b  = (_Float16*)      (ws + 7864320);   // [1024][512] 1,048,576
  _Float16*       wct  = (_Float16*)      (ws + 8912896);   // [64][512]      65,536
  float*          b23  = (float*)         (ws + 8978432);   // [1024]          4,096
  float*          bc4  = (float*)         (ws + 8982528);   // [64]              256
  _Float16*       Hsb  = (_Float16*)      (ws + 8982784);   // [160][1024]   327,680
  _Float16*       w23t = (_Float16*)      (ws + 9310464);   // [1024][1024] 2,097,152
  _Float16*       w4ct = (_Float16*)      (ws + 11407616);  // [64][1024]    131,072
  _Float16*       ub   = (_Float16*)      (ws + 11538688);  // [160][1024]   327,680

  // K0: all casts/transposes + bias folds (one launch)
  prep_all<<<4389, 256, 0, stream>>>(x_in, W1, W2, W3, W4, Wc, b2, b3, b4, bc,
                                     xbf, w1t, w2b, w3t, w4b, wct, b23, bc4);

  // K1: group compute (512 blocks) + overlapped weight-product GEMMs (272 blocks)
  group_wgemm<<<784, 256, 0, stream>>>(xbf, w1t, tidx, b1, Hsb,
                                       w3t, w2b, wct, w4b, w23t, w4ct);

  // K2: u = relu(Hs @ W23 + b23)
  mid_gemm<<<dim3(16, 2), 256, 0, stream>>>(Hsb, w23t, b23, ub);

  // K3: softmax(u @ W4c + bc4)
  head_gemm2<<<2, 256, 0, stream>>>(ub, w4ct, bc4, out);
}